// Round 3
// baseline (4885.120 us; speedup 1.0000x reference)
//
#include <hip/hip_runtime.h>
#include <stdint.h>

// ---------------- problem constants ----------------
#define NBLK   256         // workgroups: 64 rowgroups x 4 colgroups, 1 per CU
#define NTHR   512         // 8 waves
#define ROWS   16          // batch rows per WG
#define NCOL   128         // output cols per WG
#define S      512
#define KSZ    (1024*512)  // floats per k-slot
#define NELEMF 524288.0f
#define CHB    32768       // bytes per weight chunk [128 n][128 k] bf16 (swizzled)
#define CHS    16384       // shorts per chunk

typedef __attribute__((ext_vector_type(4))) float  f32x4;
typedef __attribute__((ext_vector_type(8))) short  short8;
typedef __attribute__((ext_vector_type(4))) short  s16x4;
typedef __attribute__((ext_vector_type(8))) __bf16 bf16x8;
union frag_u { short8 s; bf16x8 b; };

typedef const __attribute__((address_space(1))) void* gas_t;
typedef __attribute__((address_space(3))) void*       las_t;

// ---------------- d_ws layout (bytes) ----------------
#define CTR_OFF  0
#define RG_OFF   1024                    // 64 rowgroup counters, 128 B apart
#define RED_OFF  32768                   // floats: d0[256] d1[256] d2[256] err[20][256]
#define WB_OFF   65536                   // bf16 weights [3][4 cg][4 kc][128 n][128 k] swizzled
#define YALT_OFF 1703936                 // f32 [1024][512] alternate-y
#define ACTA_OFF (YALT_OFF + 2097152)    // bf16 act ping (swizzled rows)
#define ACTB_OFF (ACTA_OFF + 1048576)    // bf16 act pong
#define K_OFF    (ACTB_OFF + 1048576)    // f32 [7][1024][512] k-slots
// total = K_OFF + 7*2MB = 20,578,304 B

// dopri5 tableau
static __device__ const float C_A2[1] = {0.2f};
static __device__ const float C_A3[2] = {3.f/40.f, 9.f/40.f};
static __device__ const float C_A4[3] = {44.f/45.f, -56.f/15.f, 32.f/9.f};
static __device__ const float C_A5[4] = {19372.f/6561.f, -25360.f/2187.f, 64448.f/6561.f, -212.f/729.f};
static __device__ const float C_A6[5] = {9017.f/3168.f, -355.f/33.f, 46732.f/5247.f, 49.f/176.f, -5103.f/18656.f};
static __device__ const float C_B5[6] = {35.f/384.f, 0.f, 500.f/1113.f, 125.f/192.f, -2187.f/6784.f, 11.f/84.f};
#define E1f (71.f/57600.f)
#define E3f (-71.f/16695.f)
#define E4f (71.f/1920.f)
#define E5f (-17253.f/339200.f)
#define E6f (22.f/525.f)
#define E7f (-1.f/40.f)

#define WAITVM(n) asm volatile("s_waitcnt vmcnt(" #n ")" ::: "memory")
#define LGKM0     asm volatile("s_waitcnt lgkmcnt(0)" ::: "memory")
#define SB0       __builtin_amdgcn_sched_barrier(0)
#define BAR       __builtin_amdgcn_s_barrier()

__device__ __forceinline__ short f2bf(float f) {
  union { float f; uint32_t u; } v; v.f = f;
  uint32_t u = v.u;
  return (short)((u + 0x7fffu + ((u >> 16) & 1u)) >> 16);   // RNE
}

__device__ __forceinline__ float block_sum(float v, float* sred) {
  #pragma unroll
  for (int o = 32; o > 0; o >>= 1) v += __shfl_down(v, o, 64);
  const int wv = threadIdx.x >> 6;
  if ((threadIdx.x & 63) == 0) sred[wv] = v;
  __syncthreads();
  if (threadIdx.x == 0) {
    float s = 0.f;
    for (int i = 0; i < 8; ++i) s += sred[i];
    sred[8] = s;
  }
  __syncthreads();
  float r = sred[8];
  __syncthreads();
  return r;
}

// 32 KB chunk DMA: 512 thr x 16 B x 4 rounds, linear both sides
__device__ __forceinline__ void stage_chunk(const char* g0, short* lbuf) {
  const int tid = threadIdx.x;
  const char* g = g0 + (size_t)tid * 16;
  char*       l = (char*)lbuf + (size_t)tid * 16;
  #pragma unroll
  for (int r = 0; r < 4; ++r)
    __builtin_amdgcn_global_load_lds((gas_t)(uintptr_t)(g + r * 8192),
                                     (las_t)(uint32_t)(uintptr_t)(l + r * 8192), 16, 0, 0);
}

// One layer: LDS act (swizzled bf16 [16][512]) x weight chunk ring -> 16x16 tile per wave.
template<int L>
__device__ __forceinline__ void do_layer(short* Asmem, short* ring, const char* Wc,
                                         unsigned short* actNext, float* kout, float bias,
                                         int r0, int colg, int m16, int kg, int n_local,
                                         unsigned axor, unsigned bxor) {
  f32x4 acc = {0.f, 0.f, 0.f, 0.f};
  short* const sl0 = ring + ((L + 0) % 3) * CHS;
  short* const sl1 = ring + ((L + 1) % 3) * CHS;
  short* const sl2 = ring + ((L + 2) % 3) * CHS;

  auto cons = [&](int q, const short* cb) {
    #pragma unroll
    for (int ks = 0; ks < 4; ++ks) {
      unsigned ao = (((unsigned)m16 << 10) | ((unsigned)q << 8) | ((unsigned)ks << 6) | ((unsigned)kg << 4)) ^ axor;
      frag_u a; a.s = *(const short8*)((const char*)Asmem + ao);
      unsigned bo = (((unsigned)n_local << 8) | ((unsigned)ks << 6) | ((unsigned)kg << 4)) ^ bxor;
      frag_u b; b.s = *(const short8*)((const char*)cb + bo);
      acc = __builtin_amdgcn_mfma_f32_16x16x32_bf16(a.b, b.b, acc, 0, 0, 0);
    }
  };

  WAITVM(8);  SB0; BAR;            // chunk 0 landed (chunks 1,2 in flight)
  cons(0, sl0);
  LGKM0; SB0; BAR;                 // slot 0 free
  stage_chunk(Wc + 3 * (size_t)CHB, sl0);   // chunk 3 -> slot L%3
  WAITVM(8);  SB0; BAR;            // chunk 1 landed (2,3 in flight)
  cons(1, sl1);
  LGKM0; SB0; BAR;
  WAITVM(4);  SB0; BAR;            // chunk 2 landed (3 in flight)
  cons(2, sl2);
  LGKM0; SB0; BAR;
  WAITVM(0);  SB0; BAR;            // chunk 3 landed
  cons(3, sl0);
  LGKM0; SB0; BAR;

  #pragma unroll
  for (int rr = 0; rr < 4; ++rr) {
    float v = acc[rr] + bias;
    const int row_g = r0 + kg * 4 + rr;
    if constexpr (L < 2) {
      v = fmaxf(v, 0.f);
      unsigned off = ((unsigned)row_g << 10) + ((((unsigned)colg) << 1) ^ (((unsigned)(row_g & 7)) << 4));
      *(unsigned short*)((char*)actNext + off) = (unsigned short)f2bf(v);
    } else {
      kout[(size_t)row_g * 512 + colg] = v;
    }
  }
}

extern "C" __global__ void node_zero(unsigned char* ws) {
  const unsigned t = threadIdx.x;
  if (t == 0) *(unsigned*)(ws + CTR_OFF) = 0u;
  if (t < 64) *(unsigned*)(ws + RG_OFF + (size_t)t * 128) = 0u;
}

extern "C" __global__ void __launch_bounds__(NTHR)
node_main(const float* __restrict__ x,
          const float* __restrict__ W1, const float* __restrict__ b1,
          const float* __restrict__ W2, const float* __restrict__ b2,
          const float* __restrict__ W3, const float* __restrict__ b3,
          float* __restrict__ out, unsigned char* __restrict__ wsb) {
  __shared__ short ring[3 * CHS];     // 96 KiB weight ring
  __shared__ short Asmem[16 * 512];   // 16 KiB act tile (swizzled)
  __shared__ float sred[16];

  const int tid  = threadIdx.x;
  const int wg   = blockIdx.x;
  const int rg   = wg & 63;           // rowgroup
  const int c    = wg >> 6;           // colgroup
  const int r0   = rg * ROWS;
  const int cbase = c * NCOL;
  const int lane = tid & 63;
  const int wv   = tid >> 6;
  const int m16  = lane & 15;
  const int kg   = lane >> 4;
  const int n_local = wv * 16 + m16;
  const int colg = cbase + n_local;
  const unsigned axor = ((unsigned)(m16 & 7)) << 4;
  const unsigned bxor = ((unsigned)(n_local & 7)) << 4;

  unsigned* ctr = (unsigned*)(wsb + CTR_OFF);
  unsigned* rgc = (unsigned*)(wsb + RG_OFF + (size_t)rg * 128);
  float*    red = (float*)(wsb + RED_OFF);
  char*     Wbb = (char*)(wsb + WB_OFF);
  float*    yAb = (float*)(wsb + YALT_OFF);
  unsigned short* actA = (unsigned short*)(wsb + ACTA_OFF);
  unsigned short* actB = (unsigned short*)(wsb + ACTB_OFF);
  float*    kb  = (float*)(wsb + K_OFF);

  // per-thread f32x4 slot of the WG's 16x128 slice
  const size_t soff = (size_t)(r0 + (tid >> 5)) * 512 + cbase + ((tid & 31) << 2);

  const float b1v = b1[colg], b2v = b2[colg], b3v = b3[colg];

  unsigned gt  = NBLK;   // grid barrier target
  unsigned rgt = 4;      // rowgroup barrier target

  float* yloc = out;     // current y (full array; own slice via soff)
  float* yAlt = yAb;

  // ---------- grid barrier ----------
  auto gbar = [&]() {
    __threadfence(); __syncthreads();
    if (tid == 0) {
      __hip_atomic_fetch_add(ctr, 1u, __ATOMIC_ACQ_REL, __HIP_MEMORY_SCOPE_AGENT);
      while (__hip_atomic_load(ctr, __ATOMIC_ACQUIRE, __HIP_MEMORY_SCOPE_AGENT) < gt)
        __builtin_amdgcn_s_sleep(2);
    }
    __syncthreads();
    if ((tid & 63) == 0)
      (void)__hip_atomic_load(ctr, __ATOMIC_ACQUIRE, __HIP_MEMORY_SCOPE_AGENT);
    __syncthreads();
    gt += NBLK;
  };

  // ---------- rowgroup barrier (4 siblings) ----------
  auto rgbar = [&]() {
    __threadfence(); __syncthreads();
    if (tid == 0) {
      __hip_atomic_fetch_add(rgc, 1u, __ATOMIC_ACQ_REL, __HIP_MEMORY_SCOPE_AGENT);
      while (__hip_atomic_load(rgc, __ATOMIC_ACQUIRE, __HIP_MEMORY_SCOPE_AGENT) < rgt)
        __builtin_amdgcn_s_sleep(1);
    }
    BAR;
    if ((tid & 63) == 0)   // per-wave acquire: L1 invalidate for rewritten act lines
      (void)__hip_atomic_load(rgc, __ATOMIC_ACQUIRE, __HIP_MEMORY_SCOPE_AGENT);
    rgt += 4;
  };

  // DMA full act rows [16][512] bf16 (swizzled bytes, linear copy)
  auto stage_act = [&](const unsigned short* src) {
    const char* g = (const char*)src + (size_t)r0 * 1024 + (size_t)tid * 16;
    char*       l = (char*)Asmem + (size_t)tid * 16;
    #pragma unroll
    for (int rr = 0; rr < 2; ++rr)
      __builtin_amdgcn_global_load_lds((gas_t)(uintptr_t)(g + rr * 8192),
                                       (las_t)(uint32_t)(uintptr_t)(l + rr * 8192), 16, 0, 0);
  };

  auto stage3 = [&](const char* wc, int L) {
    stage_chunk(wc,               ring + ((L + 0) % 3) * CHS);
    stage_chunk(wc + (size_t)CHB, ring + ((L + 1) % 3) * CHS);
    stage_chunk(wc + 2 * (size_t)CHB, ring + ((L + 2) % 3) * CHS);
  };

  int s1s = 0, s7s = 6;

  // ---------- one f-eval: build act -> 3 layers -> k-slot ----------
  auto feval = [&](const float* coef, int nk, float dtc, float* kout, float* y5p) {
    // build own slice of y_stage
    f32x4 v = *(const f32x4*)(yloc + soff);
    for (int j = 0; j < nk; ++j) {
      const float cc = coef[j];
      if (cc == 0.f) continue;
      const int slot = (j == 0) ? s1s : ((j == 6) ? s7s : j);
      v += (cc * dtc) * *(const f32x4*)(kb + (size_t)slot * KSZ + soff);
    }
    if (y5p) *(f32x4*)(y5p + soff) = v;
    {
      s16x4 pk;
      #pragma unroll
      for (int e = 0; e < 4; ++e) pk[e] = f2bf(v[e]);
      const int row = tid >> 5;
      const unsigned cb2 = ((unsigned)(cbase + ((tid & 31) << 2))) << 1;
      const unsigned off = (((unsigned)(r0 + row)) << 10) + (cb2 ^ (((unsigned)(row & 7)) << 4));
      *(s16x4*)((char*)actA + off) = pk;
    }
    // L1
    rgbar();
    stage_act(actA);
    stage3(Wbb + (size_t)(0 * 4 + c) * 4 * CHB, 0);
    WAITVM(12); SB0; BAR;                       // act landed; chunks 0-2 in flight
    do_layer<0>(Asmem, ring, Wbb + (size_t)(0 * 4 + c) * 4 * CHB, actB, nullptr, b1v,
                r0, colg, m16, kg, n_local, axor, bxor);
    // L2
    rgbar();
    stage_act(actB);
    stage3(Wbb + (size_t)(1 * 4 + c) * 4 * CHB, 1);
    WAITVM(12); SB0; BAR;
    do_layer<1>(Asmem, ring, Wbb + (size_t)(1 * 4 + c) * 4 * CHB, actA, nullptr, b2v,
                r0, colg, m16, kg, n_local, axor, bxor);
    // L3
    rgbar();
    stage_act(actA);
    stage3(Wbb + (size_t)(2 * 4 + c) * 4 * CHB, 2);
    WAITVM(12); SB0; BAR;
    do_layer<2>(Asmem, ring, Wbb + (size_t)(2 * 4 + c) * 4 * CHB, nullptr, kout, b3v,
                r0, colg, m16, kg, n_local, axor, bxor);
    __syncthreads();   // k-slot slice visible WG-wide
  };

  auto grid_sum = [&](const float* base) {
    float v = (tid < 256) ? base[tid] : 0.f;
    return block_sum(v, sred);
  };

  // ---- Phase A: y0 init (own slice) + weight repack (192 WGs) ----
  {
    const int row = tid >> 5;
    const int col = cbase + ((tid & 31) << 2);
    f32x4 vv;
    if (col < 448) vv = *(const f32x4*)(x + (size_t)(r0 + row) * 448 + col);
    else           vv = f32x4{0.f, 0.f, 0.f, 0.f};
    *(f32x4*)(yloc + soff) = vv;
  }
  if (wg < 192) {
    float (*tr)[68] = (float (*)[68])ring;     // alias, Phase A only
    const int layer = wg >> 6;
    const int sub = wg & 63;
    const float* W = (layer == 0) ? W1 : ((layer == 1) ? W2 : W3);
    const int tk = (sub >> 3) * 64, tn = (sub & 7) * 64;
    {
      const int lr = tid >> 3, lc = (tid & 7) * 8;
      const f32x4* src = (const f32x4*)(W + (size_t)(tk + lr) * S + tn + lc);
      f32x4 a = src[0], b = src[1];
      #pragma unroll
      for (int e = 0; e < 4; ++e) { tr[lr][lc + e] = a[e]; tr[lr][lc + 4 + e] = b[e]; }
    }
    __syncthreads();
    {
      const int n = tid & 63, g8 = tid >> 6;
      short8 p;
      #pragma unroll
      for (int j = 0; j < 8; ++j) p[j] = f2bf(tr[g8 * 8 + j][n]);
      const int col = tn + n;
      const int kglob = tk + g8 * 8;
      const int cg = col >> 7, nn = col & 127;
      const int kc = kglob >> 7, ko = kglob & 127;
      const size_t chunk = ((size_t)(layer * 4 + cg) * 4 + kc);
      const unsigned off = (((unsigned)((nn << 7) | ko)) << 1) ^ (((unsigned)(nn & 7)) << 4);
      *(short8*)(Wbb + chunk * CHB + off) = p;
    }
    __syncthreads();
  }
  gbar();                                                    // barrier 1

  // ---- f0 -> slot0; d0,d1 ----
  feval(nullptr, 0, 0.f, kb, nullptr);
  {
    f32x4 y = *(const f32x4*)(yloc + soff);
    f32x4 f = *(const f32x4*)(kb + soff);
    float ay = 0.f, af = 0.f;
    #pragma unroll
    for (int q = 0; q < 4; ++q) {
      float sc = 1e-3f + 1e-3f * fabsf(y[q]);
      float a = y[q] / sc, b = f[q] / sc;
      ay += a * a; af += b * b;
    }
    float p0 = block_sum(ay, sred);
    float p1 = block_sum(af, sred);
    if (tid == 0) { red[wg] = p0; red[256 + wg] = p1; }
  }
  gbar();                                                    // barrier 2
  float d0, d1s, h0;
  {
    float a = grid_sum(red);
    float b = grid_sum(red + 256);
    d0 = sqrtf(a / NELEMF); d1s = sqrtf(b / NELEMF);
    h0 = (fminf(d0, d1s) < 1e-5f) ? 1e-6f : 0.01f * d0 / fmaxf(d1s, 1e-12f);
  }

  // ---- f1 -> slot1; d2 ----
  {
    const float onec[1] = {1.f};
    feval(onec, 1, h0, kb + (size_t)1 * KSZ, nullptr);
  }
  {
    f32x4 y  = *(const f32x4*)(yloc + soff);
    f32x4 f0 = *(const f32x4*)(kb + soff);
    f32x4 f1 = *(const f32x4*)(kb + (size_t)1 * KSZ + soff);
    float acc2 = 0.f;
    #pragma unroll
    for (int q = 0; q < 4; ++q) {
      float sc = 1e-3f + 1e-3f * fabsf(y[q]);
      float d = (f1[q] - f0[q]) / sc;
      acc2 += d * d;
    }
    float p2 = block_sum(acc2, sred);
    if (tid == 0) red[512 + wg] = p2;
  }
  gbar();                                                    // barrier 3
  float dt;
  {
    float s = grid_sum(red + 512);
    float d2 = sqrtf(s / NELEMF) / h0;
    float dmax = fmaxf(d1s, d2);
    float h1 = (dmax <= 1e-15f) ? fmaxf(1e-6f, h0 * 1e-3f)
                                : powf(0.01f / fmaxf(dmax, 1e-12f), 0.2f);
    dt = fminf(fminf(100.f * h0, h1), 1.f);
  }

  // ---- integration loop ----
  float tcur = 0.f;
  int done = 0;
  for (int step = 0; step < 20; ++step) {
    const float dtc = fminf(dt, 1.f - tcur);
    feval(C_A2, 1, dtc, kb + (size_t)1 * KSZ, nullptr);
    feval(C_A3, 2, dtc, kb + (size_t)2 * KSZ, nullptr);
    feval(C_A4, 3, dtc, kb + (size_t)3 * KSZ, nullptr);
    feval(C_A5, 4, dtc, kb + (size_t)4 * KSZ, nullptr);
    feval(C_A6, 5, dtc, kb + (size_t)5 * KSZ, nullptr);
    feval(C_B5, 6, dtc, kb + (size_t)s7s * KSZ, yAlt);   // y5 -> yAlt, then FSAL k7 into s7s
    // NOTE: stage 7 (FSAL) must eval f at y5: y5 already in yAlt; build from yAlt directly:
    {
      // f(y5): y5 = yAlt; swap roles temporarily via coef nk=0 on yAlt
      float* ysave = yloc;
      yloc = yAlt;
      feval(nullptr, 0, 0.f, kb + (size_t)s7s * KSZ, nullptr);
      yloc = ysave;
    }

    // error norm over own slice
    {
      f32x4 yv  = *(const f32x4*)(yloc + soff);
      f32x4 y5v = *(const f32x4*)(yAlt + soff);
      f32x4 k1 = *(const f32x4*)(kb + (size_t)s1s * KSZ + soff);
      f32x4 k3 = *(const f32x4*)(kb + (size_t)2   * KSZ + soff);
      f32x4 k4 = *(const f32x4*)(kb + (size_t)3   * KSZ + soff);
      f32x4 k5 = *(const f32x4*)(kb + (size_t)4   * KSZ + soff);
      f32x4 k6 = *(const f32x4*)(kb + (size_t)5   * KSZ + soff);
      f32x4 k7 = *(const f32x4*)(kb + (size_t)s7s * KSZ + soff);
      f32x4 e = E1f * k1 + E3f * k3 + E4f * k4 + E5f * k5 + E6f * k6 + E7f * k7;
      float acc2 = 0.f;
      #pragma unroll
      for (int q = 0; q < 4; ++q) {
        float ee = dtc * e[q];
        float sc = 1e-3f + 1e-3f * fmaxf(fabsf(yv[q]), fabsf(y5v[q]));
        float rr = ee / sc;
        acc2 += rr * rr;
      }
      float p = block_sum(acc2, sred);
      if (tid == 0) red[768 + step * 256 + wg] = p;
    }
    gbar();                                                  // per-step barrier
    float err_norm;
    { err_norm = sqrtf(grid_sum(red + 768 + step * 256) / NELEMF); }

    const int accept = (err_norm <= 1.0f);
    const float en = fmaxf(err_norm, 1e-10f);
    float fac = 0.9f * powf(en, -0.2f);
    fac = fminf(fmaxf(fac, 0.2f), 10.0f);
    const float dt_next = dtc * fac;
    const int done_new = done | (accept && (tcur + dtc >= 1.f - 1e-7f));
    if (!done) {
      if (accept) {
        tcur += dtc;
        float* tp = yloc; yloc = yAlt; yAlt = tp;
        int ts = s1s; s1s = s7s; s7s = ts;
      }
      dt = dt_next;
    }
    done = done_new;
    if (done) break;
  }

  // ---- final: ensure result slice is in d_out ----
  if (yloc != out) {
    *(f32x4*)(out + soff) = *(const f32x4*)(yloc + soff);
  }
}

extern "C" void kernel_launch(void* const* d_in, const int* in_sizes, int n_in,
                              void* d_out, int out_size, void* d_ws, size_t ws_size,
                              hipStream_t stream) {
  const float* x  = (const float*)d_in[0];
  const float* W1 = (const float*)d_in[1];
  const float* b1 = (const float*)d_in[2];
  const float* W2 = (const float*)d_in[3];
  const float* b2 = (const float*)d_in[4];
  const float* W3 = (const float*)d_in[5];
  const float* b3 = (const float*)d_in[6];
  unsigned char* ws = (unsigned char*)d_ws;

  hipLaunchKernelGGL(node_zero, dim3(1), dim3(64), 0, stream, ws);
  hipLaunchKernelGGL(node_main, dim3(NBLK), dim3(NTHR), 0, stream,
                     x, W1, b1, W2, b2, W3, b3, (float*)d_out, ws);
}

// Round 4
// 1572.944 us; speedup vs baseline: 3.1057x; 3.1057x over previous
//
#include <hip/hip_runtime.h>
#include <stdint.h>

// ---------------- problem constants ----------------
#define NBLK   256         // 1 block per CU (16 waves @ <=128 VGPR cannot co-reside)
#define NTHR   1024        // 16 waves
#define ROWS   4           // batch rows per block (256*4 = 1024)
#define S      512
#define KSZ    (1024*512)  // floats per k-slot
#define NELEMF 524288.0f

typedef __attribute__((ext_vector_type(2))) float  f32x2;
typedef __attribute__((ext_vector_type(4))) float  f32x4;
typedef __attribute__((ext_vector_type(8))) short  short8;
typedef __attribute__((ext_vector_type(4))) short  s16x4;
typedef __attribute__((ext_vector_type(8))) __bf16 bf16x8;
union frag_u { short8 s; bf16x8 b; };

// ---------------- d_ws layout (bytes) ----------------
#define CTR_OFF  0
#define RED_OFF  256                     // floats: d0[256] d1[256] d2[256] err[20][256]
#define WB_OFF   65536                   // bf16 weights [3][512 n][512 k]
#define YALT_OFF (WB_OFF + 3*S*S*2)      // f32 [1024][512] alternate-y
#define K_OFF    (YALT_OFF + KSZ*4)      // f32 [7][1024][512] k-slots
// total ~18.4 MB

// dopri5 tableau
static __device__ const float C_A2[1] = {0.2f};
static __device__ const float C_A3[2] = {3.f/40.f, 9.f/40.f};
static __device__ const float C_A4[3] = {44.f/45.f, -56.f/15.f, 32.f/9.f};
static __device__ const float C_A5[4] = {19372.f/6561.f, -25360.f/2187.f, 64448.f/6561.f, -212.f/729.f};
static __device__ const float C_A6[5] = {9017.f/3168.f, -355.f/33.f, 46732.f/5247.f, 49.f/176.f, -5103.f/18656.f};
static __device__ const float C_B5[6] = {35.f/384.f, 0.f, 500.f/1113.f, 125.f/192.f, -2187.f/6784.f, 11.f/84.f};
#define E1f (71.f/57600.f)
#define E3f (-71.f/16695.f)
#define E4f (71.f/1920.f)
#define E5f (-17253.f/339200.f)
#define E6f (22.f/525.f)
#define E7f (-1.f/40.f)

__device__ __forceinline__ short f2bf(float f) {
  union { float f; uint32_t u; } v; v.f = f;
  uint32_t u = v.u;
  return (short)((u + 0x7fffu + ((u >> 16) & 1u)) >> 16);   // RNE
}

extern "C" __global__ void node_zero(unsigned char* ws) {
  if (threadIdx.x == 0) *(unsigned*)(ws + CTR_OFF) = 0u;
}

extern "C" __global__ void __launch_bounds__(NTHR, 4)
node_main(const float* __restrict__ x,
          const float* __restrict__ W1, const float* __restrict__ b1,
          const float* __restrict__ W2, const float* __restrict__ b2,
          const float* __restrict__ W3, const float* __restrict__ b3,
          float* __restrict__ out, unsigned char* __restrict__ wsb) {
  __shared__ union {
    float tr[64][68];                       // Phase A transpose staging
    struct { short P[ROWS][520]; short Q[ROWS][520]; } act;
  } sh;
  __shared__ float sred[24];

  const int tid  = threadIdx.x;
  const int wg   = blockIdx.x;
  const int r0   = wg * ROWS;
  const int lane = tid & 63;
  const int wv   = tid >> 6;              // 0..15
  const int m16  = lane & 15;
  const int kg   = lane >> 4;             // 0..3
  const int n0   = wv * 32;               // 32 output cols per wave

  unsigned* ctr = (unsigned*)(wsb + CTR_OFF);
  float*    red = (float*)(wsb + RED_OFF);
  short*    Wb  = (short*)(wsb + WB_OFF);
  float*    yAb = (float*)(wsb + YALT_OFF);
  float*    kb  = (float*)(wsb + K_OFF);

  // per-thread 2-float slot of the block's 4x512 slice
  const int srow = tid >> 8;              // 0..3
  const int scol = (tid & 255) * 2;       // 0..510
  const size_t soff = (size_t)(r0 + srow) * S + scol;

  const float b1v0 = b1[n0 + m16],      b1v1 = b1[n0 + 16 + m16];
  const float b2v0 = b2[n0 + m16],      b2v1 = b2[n0 + 16 + m16];
  const float b3v0 = b3[n0 + m16],      b3v1 = b3[n0 + 16 + m16];

  unsigned gt = NBLK;
  float* yloc = out;
  float* yAlt = yAb;
  int s1s = 0, s7s = 6;

  short (*actP)[520] = sh.act.P;
  short (*actQ)[520] = sh.act.Q;

  // ---------- grid barrier (device-scope; ~1 per RK step) ----------
  auto gbar = [&]() {
    __threadfence(); __syncthreads();
    if (tid == 0) {
      __hip_atomic_fetch_add(ctr, 1u, __ATOMIC_ACQ_REL, __HIP_MEMORY_SCOPE_AGENT);
      while (__hip_atomic_load(ctr, __ATOMIC_ACQUIRE, __HIP_MEMORY_SCOPE_AGENT) < gt)
        __builtin_amdgcn_s_sleep(2);
    }
    __syncthreads();
    if ((tid & 63) == 0)
      (void)__hip_atomic_load(ctr, __ATOMIC_ACQUIRE, __HIP_MEMORY_SCOPE_AGENT);
    __syncthreads();
    gt += NBLK;
  };

  auto block_sum = [&](float v) -> float {
    #pragma unroll
    for (int o = 32; o > 0; o >>= 1) v += __shfl_down(v, o, 64);
    if ((tid & 63) == 0) sred[tid >> 6] = v;
    __syncthreads();
    if (tid == 0) {
      float s = 0.f;
      for (int i = 0; i < 16; ++i) s += sred[i];
      sred[16] = s;
    }
    __syncthreads();
    float r = sred[16];
    __syncthreads();
    return r;
  };

  auto grid_sum = [&](const float* base) -> float {
    float v = (tid < NBLK) ? base[tid] : 0.f;
    return block_sum(v);
  };

  // ---------- one dense layer: 4x512 @ 512x512, depth-4 B prefetch ----------
  auto layer = [&](const short (*aIn)[520], short (*aOut)[520], const short* Wl,
                   float bv0, float bv1, float* kout, bool relu) {
    f32x4 acc0 = {0.f, 0.f, 0.f, 0.f}, acc1 = {0.f, 0.f, 0.f, 0.f};
    const short* w0 = Wl + (size_t)(n0 + m16) * S + kg * 8;
    const short* w1 = Wl + (size_t)(n0 + 16 + m16) * S + kg * 8;
    frag_u pb0[4], pb1[4];
    #pragma unroll
    for (int p = 0; p < 4; ++p) {
      pb0[p].s = *(const short8*)(w0 + p * 32);
      pb1[p].s = *(const short8*)(w1 + p * 32);
    }
    #pragma unroll
    for (int kt = 0; kt < 16; ++kt) {
      frag_u a; a.s = *(const short8*)&aIn[m16 & 3][kt * 32 + kg * 8];
      const int st = kt & 3;
      acc0 = __builtin_amdgcn_mfma_f32_16x16x32_bf16(a.b, pb0[st].b, acc0, 0, 0, 0);
      acc1 = __builtin_amdgcn_mfma_f32_16x16x32_bf16(a.b, pb1[st].b, acc1, 0, 0, 0);
      if (kt < 12) {
        pb0[st].s = *(const short8*)(w0 + (kt + 4) * 32);
        pb1[st].s = *(const short8*)(w1 + (kt + 4) * 32);
      }
    }
    if (kg == 0) {   // D rows 0..3 live in kg==0 lanes
      #pragma unroll
      for (int r = 0; r < 4; ++r) {
        float v0 = acc0[r] + bv0, v1 = acc1[r] + bv1;
        if (relu) { v0 = fmaxf(v0, 0.f); v1 = fmaxf(v1, 0.f); }
        if (aOut) {
          aOut[r][n0 + m16]      = f2bf(v0);
          aOut[r][n0 + 16 + m16] = f2bf(v1);
        } else {
          kout[(size_t)(r0 + r) * S + n0 + m16]      = v0;
          kout[(size_t)(r0 + r) * S + n0 + 16 + m16] = v1;
        }
      }
    }
  };

  // ---------- one f-eval: build y_stage -> 3 layers -> k-slot ----------
  auto feval = [&](const float* coef, int nk, float dtc, float* kout, float* y5p) {
    f32x2 v = *(const f32x2*)(yloc + soff);
    for (int j = 0; j < nk; ++j) {
      const float cc = coef[j];
      if (cc == 0.f) continue;
      const int slot = (j == 0) ? s1s : j;
      v += (cc * dtc) * *(const f32x2*)(kb + (size_t)slot * KSZ + soff);
    }
    if (y5p) *(f32x2*)(y5p + soff) = v;
    {
      unsigned u = ((unsigned)(unsigned short)f2bf(v[1]) << 16) |
                   (unsigned)(unsigned short)f2bf(v[0]);
      *(unsigned*)&actP[srow][scol] = u;
    }
    __syncthreads();
    layer(actP, actQ, Wb,                 b1v0, b1v1, nullptr, true);
    __syncthreads();
    layer(actQ, actP, Wb + S * S,         b2v0, b2v1, nullptr, true);
    __syncthreads();
    layer(actP, nullptr, Wb + 2 * S * S,  b3v0, b3v1, kout, false);
    __syncthreads();
  };

  // ---- Phase A: y0 = [x,0] (own slice) + weight repack (192 blocks) ----
  {
    f32x2 vv;
    if (scol < 448) vv = *(const f32x2*)(x + (size_t)(r0 + srow) * 448 + scol);
    else            vv = f32x2{0.f, 0.f};
    *(f32x2*)(yloc + soff) = vv;
  }
  if (wg < 192) {
    const int layerI = wg >> 6;
    const int sub = wg & 63;
    const float* W = (layerI == 0) ? W1 : ((layerI == 1) ? W2 : W3);
    const int tk = (sub >> 3) * 64, tn = (sub & 7) * 64;
    {
      const int lr = tid >> 4, lc = (tid & 15) * 4;
      f32x4 a = *(const f32x4*)(W + (size_t)(tk + lr) * S + tn + lc);
      #pragma unroll
      for (int e = 0; e < 4; ++e) sh.tr[lr][lc + e] = a[e];
    }
    __syncthreads();
    {
      const int n = tid & 63, g4 = tid >> 6;          // g4: 0..15, 4 k each
      s16x4 p;
      #pragma unroll
      for (int j = 0; j < 4; ++j) p[j] = f2bf(sh.tr[g4 * 4 + j][n]);
      *(s16x4*)(Wb + ((size_t)(layerI * S + tn + n) * S + tk + g4 * 4)) = p;
    }
    __syncthreads();
  }
  gbar();                                                    // barrier 1

  // ---- f0 -> slot0; d0, d1 ----
  feval(nullptr, 0, 0.f, kb, nullptr);
  {
    f32x2 y = *(const f32x2*)(yloc + soff);
    f32x2 f = *(const f32x2*)(kb + soff);
    float ay = 0.f, af = 0.f;
    #pragma unroll
    for (int q = 0; q < 2; ++q) {
      float sc = 1e-3f + 1e-3f * fabsf(y[q]);
      float a = y[q] / sc, b = f[q] / sc;
      ay += a * a; af += b * b;
    }
    float p0 = block_sum(ay);
    float p1 = block_sum(af);
    if (tid == 0) { red[wg] = p0; red[NBLK + wg] = p1; }
  }
  gbar();                                                    // barrier 2
  float d1s, h0;
  {
    float a = grid_sum(red);
    float b = grid_sum(red + NBLK);
    float d0 = sqrtf(a / NELEMF); d1s = sqrtf(b / NELEMF);
    h0 = (fminf(d0, d1s) < 1e-5f) ? 1e-6f : 0.01f * d0 / fmaxf(d1s, 1e-12f);
  }

  // ---- f1 = f(y0 + h0*f0) -> slot1; d2 ----
  {
    const float onec[1] = {1.f};
    feval(onec, 1, h0, kb + (size_t)1 * KSZ, nullptr);
  }
  {
    f32x2 y  = *(const f32x2*)(yloc + soff);
    f32x2 f0 = *(const f32x2*)(kb + soff);
    f32x2 f1 = *(const f32x2*)(kb + (size_t)1 * KSZ + soff);
    float acc2 = 0.f;
    #pragma unroll
    for (int q = 0; q < 2; ++q) {
      float sc = 1e-3f + 1e-3f * fabsf(y[q]);
      float d = (f1[q] - f0[q]) / sc;
      acc2 += d * d;
    }
    float p2 = block_sum(acc2);
    if (tid == 0) red[2 * NBLK + wg] = p2;
  }
  gbar();                                                    // barrier 3
  float dt;
  {
    float s = grid_sum(red + 2 * NBLK);
    float d2 = sqrtf(s / NELEMF) / h0;
    float dmax = fmaxf(d1s, d2);
    float h1 = (dmax <= 1e-15f) ? fmaxf(1e-6f, h0 * 1e-3f)
                                : powf(0.01f / fmaxf(dmax, 1e-12f), 0.2f);
    dt = fminf(fminf(100.f * h0, h1), 1.f);
  }

  // ---- integration loop (6 f-evals/step: B5-stage eval IS the FSAL k7) ----
  float tcur = 0.f;
  int done = 0;
  for (int step = 0; step < 20; ++step) {
    const float dtc = fminf(dt, 1.f - tcur);
    feval(C_A2, 1, dtc, kb + (size_t)1 * KSZ, nullptr);
    feval(C_A3, 2, dtc, kb + (size_t)2 * KSZ, nullptr);
    feval(C_A4, 3, dtc, kb + (size_t)3 * KSZ, nullptr);
    feval(C_A5, 4, dtc, kb + (size_t)4 * KSZ, nullptr);
    feval(C_A6, 5, dtc, kb + (size_t)5 * KSZ, nullptr);
    feval(C_B5, 6, dtc, kb + (size_t)s7s * KSZ, yAlt);   // y5 -> yAlt; k7 -> s7s

    {
      f32x2 yv  = *(const f32x2*)(yloc + soff);
      f32x2 y5v = *(const f32x2*)(yAlt + soff);
      f32x2 k1v = *(const f32x2*)(kb + (size_t)s1s * KSZ + soff);
      f32x2 k3v = *(const f32x2*)(kb + (size_t)2   * KSZ + soff);
      f32x2 k4v = *(const f32x2*)(kb + (size_t)3   * KSZ + soff);
      f32x2 k5v = *(const f32x2*)(kb + (size_t)4   * KSZ + soff);
      f32x2 k6v = *(const f32x2*)(kb + (size_t)5   * KSZ + soff);
      f32x2 k7v = *(const f32x2*)(kb + (size_t)s7s * KSZ + soff);
      f32x2 e = E1f * k1v + E3f * k3v + E4f * k4v + E5f * k5v + E6f * k6v + E7f * k7v;
      float acc2 = 0.f;
      #pragma unroll
      for (int q = 0; q < 2; ++q) {
        float ee = dtc * e[q];
        float sc = 1e-3f + 1e-3f * fmaxf(fabsf(yv[q]), fabsf(y5v[q]));
        float rr = ee / sc;
        acc2 += rr * rr;
      }
      float p = block_sum(acc2);
      if (tid == 0) red[3 * NBLK + step * NBLK + wg] = p;
    }
    gbar();                                                  // per-step barrier
    float err_norm = sqrtf(grid_sum(red + 3 * NBLK + step * NBLK) / NELEMF);

    const int accept = (err_norm <= 1.0f);
    const float en = fmaxf(err_norm, 1e-10f);
    float fac = 0.9f * powf(en, -0.2f);
    fac = fminf(fmaxf(fac, 0.2f), 10.0f);
    const float dt_next = dtc * fac;
    const int done_new = done | (accept && (tcur + dtc >= 1.f - 1e-7f));
    if (!done) {
      if (accept) {
        tcur += dtc;
        float* tp = yloc; yloc = yAlt; yAlt = tp;
        int ts = s1s; s1s = s7s; s7s = ts;
      }
      dt = dt_next;
    }
    done = done_new;
    if (done) break;
  }

  // ---- final: ensure result slice is in d_out ----
  if (yloc != out) {
    *(f32x2*)(out + soff) = *(const f32x2*)(yloc + soff);
  }
}

extern "C" void kernel_launch(void* const* d_in, const int* in_sizes, int n_in,
                              void* d_out, int out_size, void* d_ws, size_t ws_size,
                              hipStream_t stream) {
  const float* x  = (const float*)d_in[0];
  const float* W1 = (const float*)d_in[1];
  const float* b1 = (const float*)d_in[2];
  const float* W2 = (const float*)d_in[3];
  const float* b2 = (const float*)d_in[4];
  const float* W3 = (const float*)d_in[5];
  const float* b3 = (const float*)d_in[6];
  unsigned char* ws = (unsigned char*)d_ws;

  hipLaunchKernelGGL(node_zero, dim3(1), dim3(64), 0, stream, ws);
  hipLaunchKernelGGL(node_main, dim3(NBLK), dim3(NTHR), 0, stream,
                     x, W1, b1, W2, b2, W3, b3, (float*)d_out, ws);
}

// Round 5
// 1085.713 us; speedup vs baseline: 4.4995x; 1.4488x over previous
//
#include <hip/hip_runtime.h>
#include <stdint.h>

// ---------------- problem constants ----------------
#define NBLK   256         // 1 block per CU
#define NTHR   1024        // 16 waves
#define ROWS   4           // batch rows per block (256*4 = 1024)
#define S      512
#define KSZ    (1024*512)  // floats per k-slot
#define NELEMF 524288.0f
#define CHB    65536       // bytes per weight chunk: [512 n][64 k] bf16, XOR-swizzled
#define NCHK   24          // chunks per f-eval (3 layers x 8)

typedef __attribute__((ext_vector_type(2))) float  f32x2;
typedef __attribute__((ext_vector_type(4))) float  f32x4;
typedef __attribute__((ext_vector_type(8))) short  short8;
typedef __attribute__((ext_vector_type(4))) short  s16x4;
typedef __attribute__((ext_vector_type(8))) __bf16 bf16x8;
union frag_u { short8 s; bf16x8 b; };

typedef const __attribute__((address_space(1))) void* gas_t;
typedef __attribute__((address_space(3))) void*       las_t;

// ---------------- d_ws layout (bytes) ----------------
#define CTR_OFF  0
#define RED_OFF  256                       // floats: d0[256] d1[256] d2[256] err[20][256]
#define WB_OFF   65536                     // bf16 [24 chunks][512 n][64 k] swizzled
#define YALT_OFF (WB_OFF + NCHK*CHB)       // f32 [1024][512] alternate-y
#define K_OFF    (YALT_OFF + KSZ*4)        // f32 [7][1024][512] k-slots

// dopri5 tableau
static __device__ const float C_A2[1] = {0.2f};
static __device__ const float C_A3[2] = {3.f/40.f, 9.f/40.f};
static __device__ const float C_A4[3] = {44.f/45.f, -56.f/15.f, 32.f/9.f};
static __device__ const float C_A5[4] = {19372.f/6561.f, -25360.f/2187.f, 64448.f/6561.f, -212.f/729.f};
static __device__ const float C_A6[5] = {9017.f/3168.f, -355.f/33.f, 46732.f/5247.f, 49.f/176.f, -5103.f/18656.f};
static __device__ const float C_B5[6] = {35.f/384.f, 0.f, 500.f/1113.f, 125.f/192.f, -2187.f/6784.f, 11.f/84.f};
#define E1f (71.f/57600.f)
#define E3f (-71.f/16695.f)
#define E4f (71.f/1920.f)
#define E5f (-17253.f/339200.f)
#define E6f (22.f/525.f)
#define E7f (-1.f/40.f)

#define WAITVM(n) asm volatile("s_waitcnt vmcnt(" #n ")" ::: "memory")
#define LGKM0     asm volatile("s_waitcnt lgkmcnt(0)" ::: "memory")
#define SB0       __builtin_amdgcn_sched_barrier(0)
#define BAR       __builtin_amdgcn_s_barrier()

__device__ __forceinline__ short f2bf(float f) {
  union { float f; uint32_t u; } v; v.f = f;
  uint32_t u = v.u;
  return (short)((u + 0x7fffu + ((u >> 16) & 1u)) >> 16);   // RNE
}

extern "C" __global__ void node_zero(unsigned char* ws) {
  if (threadIdx.x == 0) *(unsigned*)(ws + CTR_OFF) = 0u;
}

extern "C" __global__ void __launch_bounds__(NTHR, 4)
node_main(const float* __restrict__ x,
          const float* __restrict__ W1, const float* __restrict__ b1,
          const float* __restrict__ W2, const float* __restrict__ b2,
          const float* __restrict__ W3, const float* __restrict__ b3,
          float* __restrict__ out, unsigned char* __restrict__ wsb) {
  __shared__ short ring[2 * 32768];        // 128 KiB: 2-slot chunk ring (Phase A: aliases tr)
  __shared__ short actS[2][ROWS][528];     // bf16 act ping/pong, stride 528 (bank-spread)
  __shared__ float sred[24];

  const int tid  = threadIdx.x;
  const int wg   = blockIdx.x;
  const int r0   = wg * ROWS;
  const int lane = tid & 63;
  const int wv   = tid >> 6;               // 0..15
  const int m16  = lane & 15;
  const int kg   = lane >> 4;              // 0..3
  const int n0   = wv * 32;                // 32 output cols per wave
  const int arowB = (m16 & 3) * 1056;      // act row byte offset
  const unsigned m7 = (unsigned)(m16 & 7);
  const unsigned bcolB = (unsigned)(n0 + m16) * 128u;

  unsigned* ctr = (unsigned*)(wsb + CTR_OFF);
  float*    red = (float*)(wsb + RED_OFF);
  char*     Wbb = (char*)(wsb + WB_OFF);
  float*    yAb = (float*)(wsb + YALT_OFF);
  float*    kb  = (float*)(wsb + K_OFF);

  // per-thread 2-float slot of the block's 4x512 slice
  const int srow = tid >> 8;               // 0..3
  const int scol = (tid & 255) * 2;        // 0..510
  const size_t soff = (size_t)(r0 + srow) * S + scol;

  const float b1v0 = b1[n0 + m16], b1v1 = b1[n0 + 16 + m16];
  const float b2v0 = b2[n0 + m16], b2v1 = b2[n0 + 16 + m16];
  const float b3v0 = b3[n0 + m16], b3v1 = b3[n0 + 16 + m16];

  unsigned gt = NBLK;
  float* yloc = out;
  float* yAlt = yAb;
  int s1s = 0, s7s = 6;

  // ---------- grid barrier ----------
  auto gbar = [&]() {
    __threadfence(); __syncthreads();
    if (tid == 0) {
      __hip_atomic_fetch_add(ctr, 1u, __ATOMIC_ACQ_REL, __HIP_MEMORY_SCOPE_AGENT);
      while (__hip_atomic_load(ctr, __ATOMIC_ACQUIRE, __HIP_MEMORY_SCOPE_AGENT) < gt)
        __builtin_amdgcn_s_sleep(2);
    }
    __syncthreads();
    if ((tid & 63) == 0)
      (void)__hip_atomic_load(ctr, __ATOMIC_ACQUIRE, __HIP_MEMORY_SCOPE_AGENT);
    __syncthreads();
    gt += NBLK;
  };

  auto block_sum = [&](float v) -> float {
    #pragma unroll
    for (int o = 32; o > 0; o >>= 1) v += __shfl_down(v, o, 64);
    if ((tid & 63) == 0) sred[tid >> 6] = v;
    __syncthreads();
    if (tid == 0) {
      float s = 0.f;
      for (int i = 0; i < 16; ++i) s += sred[i];
      sred[16] = s;
    }
    __syncthreads();
    float r = sred[16];
    __syncthreads();
    return r;
  };

  auto grid_sum = [&](const float* base) -> float {
    float v = (tid < NBLK) ? base[tid] : 0.f;
    return block_sum(v);
  };

  // DMA one 64 KB chunk into ring slot g&1 (linear both sides)
  auto stage = [&](int g) {
    const char* gsrc = Wbb + (size_t)g * CHB + (size_t)tid * 16;
    char* ldst = (char*)ring + (size_t)(g & 1) * CHB + (size_t)tid * 16;
    #pragma unroll
    for (int r = 0; r < 4; ++r)
      __builtin_amdgcn_global_load_lds((gas_t)(uintptr_t)(gsrc + r * 16384),
                                       (las_t)(uint32_t)(uintptr_t)(ldst + r * 16384),
                                       16, 0, 0);
  };

  // ---------- one f-eval: build y_stage -> 24-chunk DMA pipeline -> k-slot ----------
  auto feval = [&](const float* coef, int nk, float dtc, float* kout, float* y5p) {
    // build own slice of y_stage (global reads, compiler-waited)
    f32x2 v = *(const f32x2*)(yloc + soff);
    for (int j = 0; j < nk; ++j) {
      const float cc = coef[j];
      if (cc == 0.f) continue;
      const int slot = (j == 0) ? s1s : j;
      v += (cc * dtc) * *(const f32x2*)(kb + (size_t)slot * KSZ + soff);
    }
    if (y5p) *(f32x2*)(y5p + soff) = v;
    // start the weight pipeline (overlaps pack + barrier)
    stage(0); stage(1);
    {
      unsigned u = ((unsigned)(unsigned short)f2bf(v[1]) << 16) |
                   (unsigned)(unsigned short)f2bf(v[0]);
      *(unsigned*)((char*)&actS[0][0][0] + srow * 1056 + scol * 2) = u;
    }
    LGKM0; SB0; BAR;      // act visible block-wide (no vmcnt drain)

    f32x4 acc0 = {0.f, 0.f, 0.f, 0.f}, acc1 = {0.f, 0.f, 0.f, 0.f};
    for (int g = 0; g < NCHK; ++g) {
      if (g < NCHK - 1) { WAITVM(4); } else { WAITVM(0); }   // chunk g landed
      SB0; BAR;
      {
        const short* sb = ring + (g & 1) * 32768;
        const char* aBuf = (const char*)&actS[(g >= 8 && g < 16) ? 1 : 0][0][0];
        const int kb2 = (g & 7) * 128;
        #pragma unroll
        for (int kt = 0; kt < 2; ++kt) {
          frag_u a; a.s = *(const short8*)(aBuf + arowB + kb2 + kt * 64 + kg * 16);
          const unsigned uu = (((unsigned)(kt * 4 + kg)) ^ m7) * 16u;
          const char* bp = (const char*)sb + bcolB + uu;
          frag_u bq0; bq0.s = *(const short8*)bp;
          frag_u bq1; bq1.s = *(const short8*)(bp + 2048);
          acc0 = __builtin_amdgcn_mfma_f32_16x16x32_bf16(a.b, bq0.b, acc0, 0, 0, 0);
          acc1 = __builtin_amdgcn_mfma_f32_16x16x32_bf16(a.b, bq1.b, acc1, 0, 0, 0);
        }
      }
      LGKM0; SB0; BAR;                       // all waves done reading slot g&1
      if (g < NCHK - 2) stage(g + 2);        // refill freed slot
      if (g == 7 || g == 15) {               // layer boundary: relu + act swap
        const float bA = (g == 7) ? b1v0 : b2v0;
        const float bB = (g == 7) ? b1v1 : b2v1;
        short* aNext = (short*)&actS[(g == 7) ? 1 : 0][0][0];
        if (kg == 0) {
          #pragma unroll
          for (int r = 0; r < 4; ++r) {
            *(short*)((char*)aNext + r * 1056 + (n0 + m16) * 2)      = f2bf(fmaxf(acc0[r] + bA, 0.f));
            *(short*)((char*)aNext + r * 1056 + (n0 + 16 + m16) * 2) = f2bf(fmaxf(acc1[r] + bB, 0.f));
          }
        }
        acc0 = f32x4{0.f, 0.f, 0.f, 0.f};
        acc1 = f32x4{0.f, 0.f, 0.f, 0.f};
        LGKM0; SB0; BAR;                     // act writes visible
      }
    }
    // layer-2 epilogue: k output (f32, global)
    if (kg == 0) {
      #pragma unroll
      for (int r = 0; r < 4; ++r) {
        kout[(size_t)(r0 + r) * S + n0 + m16]      = acc0[r] + b3v0;
        kout[(size_t)(r0 + r) * S + n0 + 16 + m16] = acc1[r] + b3v1;
      }
    }
    __syncthreads();   // full drain; k-slot slice visible block-wide
  };

  // ---- Phase A: y0 = [x,0] (own slice) + weight repack (192 blocks) ----
  {
    f32x2 vv;
    if (scol < 448) vv = *(const f32x2*)(x + (size_t)(r0 + srow) * 448 + scol);
    else            vv = f32x2{0.f, 0.f};
    *(f32x2*)(yloc + soff) = vv;
  }
  if (wg < 192) {
    float (*tr)[68] = (float (*)[68])ring;   // alias, Phase A only
    const int layerI = wg >> 6;
    const int sub = wg & 63;
    const float* W = (layerI == 0) ? W1 : ((layerI == 1) ? W2 : W3);
    const int tk = (sub >> 3) * 64, tn = (sub & 7) * 64;
    {
      const int lr = tid >> 4, lc = (tid & 15) * 4;
      f32x4 a = *(const f32x4*)(W + (size_t)(tk + lr) * S + tn + lc);
      #pragma unroll
      for (int e = 0; e < 4; ++e) tr[lr][lc + e] = a[e];
    }
    __syncthreads();
    {
      const int n = tid & 63, g4 = tid >> 6;          // g4: 0..15, 4 k each
      s16x4 p;
      #pragma unroll
      for (int j = 0; j < 4; ++j) p[j] = f2bf(tr[g4 * 4 + j][n]);
      const int ncol = tn + n;
      const int kk = tk + g4 * 4;
      const int kc = kk >> 6;                         // chunk within layer
      const int kin = kk & 63;
      const unsigned u = (unsigned)(kin >> 3);
      const unsigned h = (unsigned)((kin >> 2) & 1);
      size_t byte = ((size_t)(layerI * 8 + kc) * 512 + ncol) * 128
                  + ((u ^ (unsigned)(ncol & 7)) * 16u + h * 8u);
      *(s16x4*)(Wbb + byte) = p;
    }
    __syncthreads();
  }
  gbar();                                                    // barrier 1

  // ---- f0 -> slot0; d0, d1 ----
  feval(nullptr, 0, 0.f, kb, nullptr);
  {
    f32x2 y = *(const f32x2*)(yloc + soff);
    f32x2 f = *(const f32x2*)(kb + soff);
    float ay = 0.f, af = 0.f;
    #pragma unroll
    for (int q = 0; q < 2; ++q) {
      float sc = 1e-3f + 1e-3f * fabsf(y[q]);
      float a = y[q] / sc, b = f[q] / sc;
      ay += a * a; af += b * b;
    }
    float p0 = block_sum(ay);
    float p1 = block_sum(af);
    if (tid == 0) { red[wg] = p0; red[NBLK + wg] = p1; }
  }
  gbar();                                                    // barrier 2
  float d1s, h0;
  {
    float a = grid_sum(red);
    float b = grid_sum(red + NBLK);
    float d0 = sqrtf(a / NELEMF); d1s = sqrtf(b / NELEMF);
    h0 = (fminf(d0, d1s) < 1e-5f) ? 1e-6f : 0.01f * d0 / fmaxf(d1s, 1e-12f);
  }

  // ---- f1 = f(y0 + h0*f0) -> slot1; d2 ----
  {
    const float onec[1] = {1.f};
    feval(onec, 1, h0, kb + (size_t)1 * KSZ, nullptr);
  }
  {
    f32x2 y  = *(const f32x2*)(yloc + soff);
    f32x2 f0 = *(const f32x2*)(kb + soff);
    f32x2 f1 = *(const f32x2*)(kb + (size_t)1 * KSZ + soff);
    float acc2 = 0.f;
    #pragma unroll
    for (int q = 0; q < 2; ++q) {
      float sc = 1e-3f + 1e-3f * fabsf(y[q]);
      float d = (f1[q] - f0[q]) / sc;
      acc2 += d * d;
    }
    float p2 = block_sum(acc2);
    if (tid == 0) red[2 * NBLK + wg] = p2;
  }
  gbar();                                                    // barrier 3
  float dt;
  {
    float s = grid_sum(red + 2 * NBLK);
    float d2 = sqrtf(s / NELEMF) / h0;
    float dmax = fmaxf(d1s, d2);
    float h1 = (dmax <= 1e-15f) ? fmaxf(1e-6f, h0 * 1e-3f)
                                : powf(0.01f / fmaxf(dmax, 1e-12f), 0.2f);
    dt = fminf(fminf(100.f * h0, h1), 1.f);
  }

  // ---- integration loop (6 f-evals/step; B5-stage eval IS the FSAL k7) ----
  float tcur = 0.f;
  int done = 0;
  for (int step = 0; step < 20; ++step) {
    const float dtc = fminf(dt, 1.f - tcur);
    feval(C_A2, 1, dtc, kb + (size_t)1 * KSZ, nullptr);
    feval(C_A3, 2, dtc, kb + (size_t)2 * KSZ, nullptr);
    feval(C_A4, 3, dtc, kb + (size_t)3 * KSZ, nullptr);
    feval(C_A5, 4, dtc, kb + (size_t)4 * KSZ, nullptr);
    feval(C_A6, 5, dtc, kb + (size_t)5 * KSZ, nullptr);
    feval(C_B5, 6, dtc, kb + (size_t)s7s * KSZ, yAlt);   // y5 -> yAlt; k7 -> s7s

    {
      f32x2 yv  = *(const f32x2*)(yloc + soff);
      f32x2 y5v = *(const f32x2*)(yAlt + soff);
      f32x2 k1v = *(const f32x2*)(kb + (size_t)s1s * KSZ + soff);
      f32x2 k3v = *(const f32x2*)(kb + (size_t)2   * KSZ + soff);
      f32x2 k4v = *(const f32x2*)(kb + (size_t)3   * KSZ + soff);
      f32x2 k5v = *(const f32x2*)(kb + (size_t)4   * KSZ + soff);
      f32x2 k6v = *(const f32x2*)(kb + (size_t)5   * KSZ + soff);
      f32x2 k7v = *(const f32x2*)(kb + (size_t)s7s * KSZ + soff);
      f32x2 e = E1f * k1v + E3f * k3v + E4f * k4v + E5f * k5v + E6f * k6v + E7f * k7v;
      float acc2 = 0.f;
      #pragma unroll
      for (int q = 0; q < 2; ++q) {
        float ee = dtc * e[q];
        float sc = 1e-3f + 1e-3f * fmaxf(fabsf(yv[q]), fabsf(y5v[q]));
        float rr = ee / sc;
        acc2 += rr * rr;
      }
      float p = block_sum(acc2);
      if (tid == 0) red[3 * NBLK + step * NBLK + wg] = p;
    }
    gbar();                                                  // per-step barrier
    float err_norm = sqrtf(grid_sum(red + 3 * NBLK + step * NBLK) / NELEMF);

    const int accept = (err_norm <= 1.0f);
    const float en = fmaxf(err_norm, 1e-10f);
    float fac = 0.9f * powf(en, -0.2f);
    fac = fminf(fmaxf(fac, 0.2f), 10.0f);
    const float dt_next = dtc * fac;
    const int done_new = done | (accept && (tcur + dtc >= 1.f - 1e-7f));
    if (!done) {
      if (accept) {
        tcur += dtc;
        float* tp = yloc; yloc = yAlt; yAlt = tp;
        int ts = s1s; s1s = s7s; s7s = ts;
      }
      dt = dt_next;
    }
    done = done_new;
    if (done) break;
  }

  // ---- final: ensure result slice is in d_out ----
  if (yloc != out) {
    *(f32x2*)(out + soff) = *(const f32x2*)(yloc + soff);
  }
}

extern "C" void kernel_launch(void* const* d_in, const int* in_sizes, int n_in,
                              void* d_out, int out_size, void* d_ws, size_t ws_size,
                              hipStream_t stream) {
  const float* x  = (const float*)d_in[0];
  const float* W1 = (const float*)d_in[1];
  const float* b1 = (const float*)d_in[2];
  const float* W2 = (const float*)d_in[3];
  const float* b2 = (const float*)d_in[4];
  const float* W3 = (const float*)d_in[5];
  const float* b3 = (const float*)d_in[6];
  unsigned char* ws = (unsigned char*)d_ws;

  hipLaunchKernelGGL(node_zero, dim3(1), dim3(64), 0, stream, ws);
  hipLaunchKernelGGL(node_main, dim3(NBLK), dim3(NTHR), 0, stream,
                     x, W1, b1, W2, b2, W3, b3, (float*)d_out, ws);
}